// Round 1
// baseline (198.915 us; speedup 1.0000x reference)
//
#include <hip/hip_runtime.h>
#include <math.h>

// GraphLearner: per-edge cosine similarity + sigmoid + straight-through hard threshold.
//   out[e] = let v = sigmoid(cos(f1,f2)/T) in (v <= 0.5 ? 0 : v)
// 16 lanes cooperate per edge: each lane loads one float4 of each 64-float row
// (256 B row = 16 lanes x 16 B, fully coalesced), partial dots reduced via
// __shfl_xor tree within the 16-lane group.

#define D 64
#define LPE 16                      // lanes per edge
#define BLOCK 256
#define EDGES_PER_BLOCK (BLOCK / LPE)
#define COS_EPS 1e-6f

__global__ __launch_bounds__(BLOCK) void GraphLearner_68513318306086_kernel(
    const float* __restrict__ node_embs,
    const int*   __restrict__ edge_index,
    const int*   __restrict__ temp_ptr,
    float*       __restrict__ out,
    int n_edges)
{
    // temperature arrives as a 1-element array; reference passes Python int 1.
    // Robustly accept either int32 or float32 encoding.
    int tbits = *temp_ptr;
    float T;
    if (tbits >= 1 && tbits < (1 << 23)) {
        T = (float)tbits;           // small positive int -> int32 temperature
    } else {
        union { int i; float f; } u; u.i = tbits; T = u.f;  // float32 bits
    }

    int tid  = blockIdx.x * BLOCK + threadIdx.x;
    int e    = tid >> 4;            // edge index (16 lanes per edge)
    int lane = threadIdx.x & (LPE - 1);
    if (e >= n_edges) return;

    int i0 = edge_index[e];             // row 0 of edge_index: [0, E)
    int i1 = edge_index[n_edges + e];   // row 1 of edge_index: [E, 2E)

    const float4* r0 = (const float4*)(node_embs + (size_t)i0 * D);
    const float4* r1 = (const float4*)(node_embs + (size_t)i1 * D);
    float4 a = r0[lane];
    float4 b = r1[lane];

    float dot = a.x * b.x + a.y * b.y + a.z * b.z + a.w * b.w;
    float n1  = a.x * a.x + a.y * a.y + a.z * a.z + a.w * a.w;
    float n2  = b.x * b.x + b.y * b.y + b.z * b.z + b.w * b.w;

    // binary-tree reduction across the 16-lane group (pairwise order, close to
    // numpy's pairwise summation -> minimal fp divergence from the np reference)
    #pragma unroll
    for (int m = 1; m < LPE; m <<= 1) {
        dot += __shfl_xor(dot, m, LPE);
        n1  += __shfl_xor(n1,  m, LPE);
        n2  += __shfl_xor(n2,  m, LPE);
    }

    if (lane == 0) {
        float d1   = fmaxf(sqrtf(n1), COS_EPS);
        float d2   = fmaxf(sqrtf(n2), COS_EPS);
        float cosv = dot / (d1 * d2);
        float x    = cosv / T;
        float v    = 1.0f / (1.0f + expf(-x));
        out[e] = (v <= 0.5f) ? 0.0f : v;   // straight-through hard threshold
    }
}

extern "C" void kernel_launch(void* const* d_in, const int* in_sizes, int n_in,
                              void* d_out, int out_size, void* d_ws, size_t ws_size,
                              hipStream_t stream) {
    const float* node_embs = (const float*)d_in[0];
    const int*   edge_index = (const int*)d_in[1];
    const int*   temp_ptr   = (const int*)d_in[2];
    float*       out        = (float*)d_out;

    int n_edges = in_sizes[1] / 2;      // edge_index is [2, E]

    int grid = (n_edges + EDGES_PER_BLOCK - 1) / EDGES_PER_BLOCK;
    GraphLearner_68513318306086_kernel<<<grid, BLOCK, 0, stream>>>(
        node_embs, edge_index, temp_ptr, out, n_edges);
}